// Round 8
// baseline (1781.257 us; speedup 1.0000x reference)
//
#include <hip/hip_runtime.h>
#include <hip/hip_fp16.h>
#include <cstdint>
#include <cstddef>

#define B_    256
#define T_    128
#define SIG_  64
#define MET_  32
#define H_    256
#define F_    16
#define NCOL  1040   // X cols: [i:0..255 | ste:256..511 | c:512..767 | o:768..1023 | fre:1024..1039]

// U split across storage tiers (k = row index 0..255):
//   k   0..111 : registers (14 uint4/thread = 56 VGPRs)          [UR]
//   k 112..135 : LDS (12 dwords/col, stride 13 for bank spread)  [UL]
//   k 136..255 : global stream, 15 uint4/thread/step             [UG]
#define KREG 112
#define KLDS 24
#define NREG4 14        // uint4 groups in registers
#define NLDSD 12        // dwords per col in LDS
#define NGLB4 15        // uint4 groups from global
#define LSTR  13        // LDS stride (12 + 1 pad, odd => conflict-free)

__device__ __forceinline__ float hsig(float x) {
    return fminf(fmaxf(x * (1.0f/6.0f) + 0.5f, 0.0f), 1.0f);
}

__device__ __forceinline__ unsigned short f2h(float f) {
    __half h = __float2half(f);
    return *(unsigned short*)&h;
}

__device__ __forceinline__ float ntload_f(const float* p) {
    return __builtin_nontemporal_load(p);
}
__device__ __forceinline__ float4 ntload_f4(const float* p) {
    float4 v;
    v.x = __builtin_nontemporal_load(p + 0);
    v.y = __builtin_nontemporal_load(p + 1);
    v.z = __builtin_nontemporal_load(p + 2);
    v.w = __builtin_nontemporal_load(p + 3);
    return v;
}

typedef _Float16 half2v __attribute__((ext_vector_type(2)));

__device__ __forceinline__ float dot2(unsigned int u, unsigned int h, float acc) {
#if __has_builtin(__builtin_amdgcn_fdot2)
    return __builtin_amdgcn_fdot2(__builtin_bit_cast(half2v, u),
                                  __builtin_bit_cast(half2v, h), acc, false);
#else
    __half2 uu = *(__half2*)&u, hh = *(__half2*)&h;
    float2 uf = __half22float2(uu), hf = __half22float2(hh);
    return fmaf(uf.x, hf.x, fmaf(uf.y, hf.y, acc));
#endif
}

// ---------------------------------------------------------------------------
// Pack: Wcat[96][1040] f32, bcat[1040] f32, and fp16 U tiers:
//   UR: [(k>>3)][col][k&7]      k in [0,112)   (uint4 group i = k 8i..8i+7)
//   UL: [(k-112)>>1][col][k&1]  k in [112,136) (dword d = k-pair)
//   UG: [((k-136)>>3)][col][(k-136)&7]  k in [136,256)
//   UF: fre cols [col][k] (8 KB -> L1-resident)
// ---------------------------------------------------------------------------
__global__ __launch_bounds__(256) void pack_kernel(
    const float* __restrict__ Wis, const float* __restrict__ Wstes, const float* __restrict__ Wfres,
    const float* __restrict__ Wcs, const float* __restrict__ Wos,
    const float* __restrict__ Wim, const float* __restrict__ Wstem, const float* __restrict__ Wfrem,
    const float* __restrict__ Wcm, const float* __restrict__ Wom,
    const float* __restrict__ Ui, const float* __restrict__ Uste, const float* __restrict__ Ufre,
    const float* __restrict__ Uc, const float* __restrict__ Uo,
    const float* __restrict__ bi, const float* __restrict__ bste, const float* __restrict__ bfre,
    const float* __restrict__ bc, const float* __restrict__ bo,
    float* __restrict__ Wcat, float* __restrict__ bcat,
    unsigned short* __restrict__ UR, unsigned short* __restrict__ UL,
    unsigned short* __restrict__ UG, unsigned short* __restrict__ UF)
{
    int gtid = blockIdx.x * blockDim.x + threadIdx.x;
    int stride = gridDim.x * blockDim.x;
    const float* Wsig[5] = {Wis, Wstes, Wcs, Wos, Wfres};
    const float* Wmet[5] = {Wim, Wstem, Wcm, Wom, Wfrem};
    const float* Us[4]   = {Ui, Uste, Uc, Uo};
    const float* bs[5]   = {bi, bste, bc, bo, bfre};

    for (int i = gtid; i < 96*NCOL; i += stride) {
        int k = i / NCOL, n = i - k*NCOL;
        int sec, idx, secN;
        if (n < 1024) { sec = n >> 8; idx = n & 255; secN = H_; }
        else          { sec = 4; idx = n - 1024; secN = F_; }
        float v = (k < 64) ? Wsig[sec][k*secN + idx] : Wmet[sec][(k-64)*secN + idx];
        Wcat[k*NCOL + n] = v;
    }
    for (int n = gtid; n < NCOL; n += stride) {
        int sec, idx;
        if (n < 1024) { sec = n >> 8; idx = n & 255; }
        else          { sec = 4; idx = n - 1024; }
        bcat[n] = bs[sec][idx];
    }
    // main 1024 cols, tiered
    for (int i = gtid; i < 1024*H_; i += stride) {
        int col = i >> 8, k = i & 255;
        int sec = col >> 8, idx = col & 255;
        unsigned short v = f2h(Us[sec][k*H_ + idx]);
        if (k < KREG) {
            UR[(((k >> 3) * 1024) + col) * 8 + (k & 7)] = v;
        } else if (k < KREG + KLDS) {
            int kd = k - KREG;
            UL[((kd >> 1) * 1024 + col) * 2 + (kd & 1)] = v;
        } else {
            int kk = k - (KREG + KLDS);
            UG[(((kk >> 3) * 1024) + col) * 8 + (kk & 7)] = v;
        }
    }
    // fre 16 cols
    for (int i = gtid; i < 16*H_; i += stride) {
        int col = i >> 8, k = i & 255;
        UF[col*H_ + k] = f2h(Ufre[k*F_ + col]);
    }
}

// ---------------------------------------------------------------------------
// Phase 1: input projection GEMM for ALL time steps.
// ---------------------------------------------------------------------------
__global__ __launch_bounds__(256) void proj_kernel(
    const float* __restrict__ sig, const float* __restrict__ met,
    const float* __restrict__ Wcat, const float* __restrict__ bcat,
    float* __restrict__ X)
{
    __shared__ float A_s[32][128];
    __shared__ float W_s[32][128];
    int tid = threadIdx.x;
    int c0b = blockIdx.x * 128;
    int m0  = blockIdx.y * 128;
    int t0  = blockIdx.z * 16;
    int r0  = (tid >> 4) * 8;
    int c0t = (tid & 15) * 8;

    float acc[8][8];
    #pragma unroll
    for (int i = 0; i < 8; ++i)
        #pragma unroll
        for (int j = 0; j < 8; ++j) acc[i][j] = 0.0f;

    for (int k0 = 0; k0 < 96; k0 += 32) {
        for (int idx = tid; idx < 32*128; idx += 256) {
            int ml = idx & 127, kk = idx >> 7;
            int m = m0 + ml;
            int b = m >> 4, tl = m & 15;
            int g = b * T_ + t0 + tl;
            int k = k0 + kk;
            float v = (k < 64) ? sig[g*SIG_ + k] : met[g*MET_ + (k - 64)];
            A_s[kk][ml] = v;
        }
        for (int idx = tid; idx < 32*128; idx += 256) {
            int c = idx & 127, kk = idx >> 7;
            int n = c0b + c;
            W_s[kk][c] = (n < NCOL) ? Wcat[(k0+kk)*NCOL + n] : 0.0f;
        }
        __syncthreads();
        #pragma unroll
        for (int kk = 0; kk < 32; ++kk) {
            float4 a0 = *(const float4*)&A_s[kk][r0];
            float4 a1 = *(const float4*)&A_s[kk][r0+4];
            float4 w0 = *(const float4*)&W_s[kk][c0t];
            float4 w1 = *(const float4*)&W_s[kk][c0t+4];
            float av[8] = {a0.x,a0.y,a0.z,a0.w,a1.x,a1.y,a1.z,a1.w};
            float wv[8] = {w0.x,w0.y,w0.z,w0.w,w1.x,w1.y,w1.z,w1.w};
            #pragma unroll
            for (int i = 0; i < 8; ++i)
                #pragma unroll
                for (int j = 0; j < 8; ++j)
                    acc[i][j] = fmaf(av[i], wv[j], acc[i][j]);
        }
        __syncthreads();
    }
    #pragma unroll
    for (int i = 0; i < 8; ++i) {
        int m = m0 + r0 + i;
        int bb = m >> 4, tl = m & 15;
        size_t row = (size_t)bb * T_ + t0 + tl;
        #pragma unroll
        for (int j = 0; j < 8; ++j) {
            int n = c0b + c0t + j;
            if (n < NCOL) X[row*NCOL + n] = acc[i][j] + bcat[n];
        }
    }
}

// ---------------------------------------------------------------------------
// Phase 2: full recurrence, SINGLE launch, grid=256 x 1024 threads.
// R8: U pinned on-chip — 112 k-rows in registers (56 VGPRs/thread), 24 in
// LDS, only 120 streamed from L2 each step (240 B/thread vs 512 in R7).
// R7 diagnosis: VALU fixed (38%) but per-CU U-byte delivery (~78 B/cyc)
// became the wall; cutting streamed bytes 53% attacks it directly.
// WRITE_SIZE ~8B + VGPR<=128 are the no-spill invariants to watch.
// ---------------------------------------------------------------------------
__global__ __launch_bounds__(1024, 4) void recur_kernel(
    const float* __restrict__ X,
    const uint4* __restrict__ URg, const unsigned int* __restrict__ ULg,
    const uint4* __restrict__ UGg, const uint4* __restrict__ UF,
    const float* __restrict__ U_a, const float* __restrict__ b_a,
    const float* __restrict__ W_p, const float* __restrict__ b_p,
    const float* __restrict__ fc_w, const float* __restrict__ fc_b,
    float* __restrict__ out)
{
    __shared__ unsigned int ldsU[1024 * LSTR];   // 53,248 B
    __shared__ float pre_s[1024];                //  4,096 B
    __shared__ unsigned int h_p[H_/2];           //    512 B (h as fp16 pairs)
    __shared__ float qp[64];                     //    256 B
    __shared__ float cs_s[16], sn_s[16];         //    128 B

    int tid  = threadIdx.x;
    int b    = blockIdx.x;
    int lane = tid & 63;
    int wid  = tid >> 6;
    bool isfre = ((lane & 15) == 15);
    int fq = lane >> 4;                  // quarter 0..3 (when isfre)

    // update-phase ownership: j = tid>>2 (h row), f0 = (tid&3)*4 (f range)
    int j  = tid >> 2;
    int f0 = (tid & 3) * 4;

    // ---- load register-resident U slice (k 0..111 of column tid) ----
    uint4 ureg[NREG4];
    #pragma unroll
    for (int i = 0; i < NREG4; ++i) ureg[i] = URg[i * 1024 + tid];

    // ---- stage LDS-resident U slice (k 112..135) ----
    #pragma unroll
    for (int d = 0; d < NLDSD; ++d)
        ldsU[tid * LSTR + d] = ULg[d * 1024 + tid];

    if (tid < H_/2) h_p[tid] = 0u;
    if (tid < 16) {
        float ang = (float)tid * 0.39269908169872414f; // 2*pi/16
        cs_s[tid] = cosf(ang);
        sn_s[tid] = sinf(ang);
    }
    float Sre[4], Sim[4];
    #pragma unroll
    for (int r = 0; r < 4; ++r) { Sre[r] = 0.0f; Sim[r] = 0.0f; }

    float ba_j = b_a[j];
    float4 ua4 = ((const float4*)U_a)[tid & 3];
    const uint4* Uf = UF + (wid * 32 + fq * 8);   // quarter fq of fre col wid
    const float* Xb = X + (size_t)b * T_ * NCOL;
    __half* h_h = (__half*)h_p;

    float hnew = 0.0f;
    __syncthreads();

    for (int t = 0; t < T_; ++t) {
        const float* xrow = Xb + (size_t)t * NCOL;

        // ---- dot phase: pre[col=tid] = x + U[:,col] . h ----
        float acc0 = ntload_f(&xrow[tid]);
        float acc1 = 0.0f, acc2 = 0.0f;

        // global tier first (loads pipeline while reg tier computes)
        #pragma unroll
        for (int g = 0; g < NGLB4; ++g) {
            uint4 u  = UGg[g * 1024 + tid];
            uint4 hp = *(const uint4*)&h_p[(KREG + KLDS)/2 + g*4];
            acc2 = dot2(u.x, hp.x, acc2);
            acc2 = dot2(u.y, hp.y, acc2);
            acc2 = dot2(u.z, hp.z, acc2);
            acc2 = dot2(u.w, hp.w, acc2);
        }
        // register tier
        #pragma unroll
        for (int i = 0; i < NREG4; ++i) {
            uint4 hp = *(const uint4*)&h_p[i*4];
            acc0 = dot2(ureg[i].x, hp.x, acc0);
            acc0 = dot2(ureg[i].y, hp.y, acc0);
            acc0 = dot2(ureg[i].z, hp.z, acc0);
            acc0 = dot2(ureg[i].w, hp.w, acc0);
        }
        // LDS tier
        #pragma unroll
        for (int d = 0; d < NLDSD; ++d)
            acc1 = dot2(ldsU[tid * LSTR + d], h_p[KREG/2 + d], acc1);

        float acc = acc0 + acc1 + acc2;

        float fa = 0.0f;
        if (isfre) {
            #pragma unroll
            for (int q = 0; q < 8; ++q) {
                uint4 u  = Uf[q];
                uint4 hp = *(const uint4*)&h_p[fq * 32 + q * 4];
                fa = dot2(u.x, hp.x, fa);
                fa = dot2(u.y, hp.y, fa);
                fa = dot2(u.z, hp.z, fa);
                fa = dot2(u.w, hp.w, fa);
            }
        }
        pre_s[tid] = acc;
        if (isfre) qp[wid*4 + fq] = fa;
        __syncthreads();   // A: pre_s + qp ready; h reads done

        // ---- update phase ----
        float xi   = pre_s[j];
        float xste = pre_s[256 + j];
        float xc   = pre_s[512 + j];
        float xo   = pre_s[768 + j];
        float gi   = hsig(xi);
        float gste = hsig(xste);
        float go   = hsig(xo);
        float cc   = gi * tanhf(xc);

        float4 xfre = ntload_f4(&xrow[1024 + f0]);
        float4 q0 = *(const float4*)&qp[(f0+0)*4];
        float4 q1 = *(const float4*)&qp[(f0+1)*4];
        float4 q2 = *(const float4*)&qp[(f0+2)*4];
        float4 q3 = *(const float4*)&qp[(f0+3)*4];
        float fre[4];
        fre[0] = hsig(xfre.x + q0.x + q0.y + q0.z + q0.w);
        fre[1] = hsig(xfre.y + q1.x + q1.y + q1.z + q1.w);
        fre[2] = hsig(xfre.z + q2.x + q2.y + q2.z + q2.w);
        fre[3] = hsig(xfre.w + q3.x + q3.y + q3.z + q3.w);

        int tt1 = (t + 1) & 15;
        float Aa = 0.0f;
        #pragma unroll
        for (int r = 0; r < 4; ++r) {
            int idx = (tt1 * (f0 + r)) & 15;
            float dec = gste * fre[r];
            float sre = fmaf(dec, Sre[r], cc * cs_s[idx]);
            float sim = fmaf(dec, Sim[r], cc * sn_s[idx]);
            Sre[r] = sre; Sim[r] = sim;
            Aa = fmaf(fmaf(sre, sre, sim*sim), ((const float*)&ua4)[r], Aa);
        }
        Aa += __shfl_xor(Aa, 1);
        Aa += __shfl_xor(Aa, 2);
        if ((tid & 3) == 0) {
            float a = tanhf(Aa + ba_j);
            hnew = go * a;
            h_h[j] = __float2half(hnew);
        }
        __syncthreads();   // B: h ready; pre_s/qp reads done
    }

    // ---- head: out[b] = (sum_j h[j]*W_p[j] + b_p)*fc_w + fc_b ----
    if ((tid & 3) == 0) pre_s[j] = hnew * W_p[j];
    __syncthreads();
    for (int s = 128; s > 0; s >>= 1) {
        if (tid < s) pre_s[tid] += pre_s[tid + s];
        __syncthreads();
    }
    if (tid == 0) out[b] = (pre_s[0] + b_p[0]) * fc_w[0] + fc_b[0];
}

// ---------------------------------------------------------------------------
extern "C" void kernel_launch(void* const* d_in, const int* in_sizes, int n_in,
                              void* d_out, int out_size, void* d_ws, size_t ws_size,
                              hipStream_t stream) {
    const float* signal = (const float*)d_in[0];
    const float* metmast = (const float*)d_in[1];
    const float* W_i_s   = (const float*)d_in[2];
    const float* W_ste_s = (const float*)d_in[3];
    const float* W_fre_s = (const float*)d_in[4];
    const float* W_c_s   = (const float*)d_in[5];
    const float* W_o_s   = (const float*)d_in[6];
    const float* W_i_m   = (const float*)d_in[7];
    const float* W_ste_m = (const float*)d_in[8];
    const float* W_fre_m = (const float*)d_in[9];
    const float* W_c_m   = (const float*)d_in[10];
    const float* W_o_m   = (const float*)d_in[11];
    const float* U_i   = (const float*)d_in[12];
    const float* b_i   = (const float*)d_in[13];
    const float* U_ste = (const float*)d_in[14];
    const float* b_ste = (const float*)d_in[15];
    const float* U_fre = (const float*)d_in[16];
    const float* b_fre = (const float*)d_in[17];
    const float* U_c   = (const float*)d_in[18];
    const float* b_c   = (const float*)d_in[19];
    const float* U_o   = (const float*)d_in[20];
    const float* b_o   = (const float*)d_in[21];
    const float* U_a   = (const float*)d_in[22];
    const float* b_a   = (const float*)d_in[23];
    const float* W_p   = (const float*)d_in[24];
    const float* b_p   = (const float*)d_in[25];
    const float* fc_w  = (const float*)d_in[26];
    const float* fc_b  = (const float*)d_in[27];
    float* out = (float*)d_out;

    char* ws = (char*)d_ws;
    float*          Wcat = (float*)(ws + 0);                 //  96*1040*4 = 399360
    float*          bcat = (float*)(ws + 399360);            //  4160 -> 403520
    unsigned short* UR   = (unsigned short*)(ws + 403520);   //  112*1024*2 = 229376 -> 632896
    unsigned short* UL   = (unsigned short*)(ws + 632896);   //  24*1024*2  =  49152 -> 682048
    unsigned short* UG   = (unsigned short*)(ws + 682048);   //  120*1024*2 = 245760 -> 927808
    unsigned short* UF   = (unsigned short*)(ws + 927808);   //  16*256*2   =   8192 -> 936000
    float*          X    = (float*)(ws + 936000);            //  256*128*1040*4 = 136314880
    // total ~137.3 MB

    pack_kernel<<<256, 256, 0, stream>>>(
        W_i_s, W_ste_s, W_fre_s, W_c_s, W_o_s,
        W_i_m, W_ste_m, W_fre_m, W_c_m, W_o_m,
        U_i, U_ste, U_fre, U_c, U_o,
        b_i, b_ste, b_fre, b_c, b_o,
        Wcat, bcat, UR, UL, UG, UF);

    proj_kernel<<<dim3(9, 32, 8), 256, 0, stream>>>(signal, metmast, Wcat, bcat, X);

    recur_kernel<<<B_, 1024, 0, stream>>>(X,
                                          (const uint4*)UR, (const unsigned int*)UL,
                                          (const uint4*)UG, (const uint4*)UF,
                                          U_a, b_a, W_p, b_p, fc_w, fc_b, out);
}